// Round 2
// baseline (1898.301 us; speedup 1.0000x reference)
//
#include <hip/hip_runtime.h>
#include <hip/hip_bf16.h>
#include <cstdint>
#include <cstddef>

typedef __attribute__((ext_vector_type(8))) short s16x8;
typedef __attribute__((ext_vector_type(8))) unsigned short u16x8;
typedef __attribute__((ext_vector_type(4))) float f32x4;

#define DEVI static __device__ __forceinline__

constexpr int S = 4096, HID = 1024, NH = 16, HD = 64, BATCH = 8;
constexpr int MTOT = BATCH * S;  // 32768
constexpr float SCALE = 0.125f;  // 1/sqrt(64)

DEVI float bf2f(unsigned short u) {
  union { unsigned int i; float f; } v; v.i = ((unsigned int)u) << 16; return v.f;
}
DEVI unsigned short f2b(float f) {
  __hip_bfloat16 h = __float2bfloat16(f);
  return *reinterpret_cast<unsigned short*>(&h);
}

// ---------------------------------------------------------------------------
// Dual GEMM: MQ = X@Wq.T + bq (bf16 out), MK = X@Wk.T + bk (bf16 out)
// X fp32 [MTOT,HID]; W fp32 [HID,HID] row-major over n (i.e. W[n,k]).
// blockIdx.y < 8 -> Q path, else K path. Tile 128x128, BK=64, 256 thr.
// ---------------------------------------------------------------------------
__global__ __launch_bounds__(256) void gemm_dual_kernel(
    const float* __restrict__ X,
    const float* __restrict__ Wq, const float* __restrict__ Wk,
    const float* __restrict__ bq, const float* __restrict__ bk,
    __hip_bfloat16* __restrict__ MQ, __hip_bfloat16* __restrict__ MK)
{
  __shared__ unsigned short lA[128][72];
  __shared__ unsigned short lB[128][72];

  const int m0 = blockIdx.x * 128;
  const float* W; const float* bias; __hip_bfloat16* C; int n0;
  if (blockIdx.y < 8) { W = Wq; bias = bq; C = MQ; n0 = blockIdx.y * 128; }
  else                { W = Wk; bias = bk; C = MK; n0 = (blockIdx.y - 8) * 128; }

  const int t = threadIdx.x;
  const int srow = t >> 1, shalf = t & 1;
  const int lane = t & 63, wv = t >> 6;
  const int wm = wv >> 1, wn = wv & 1;
  const int lg = lane >> 4, lr = lane & 15;

  const f32x4 zero = {0.f, 0.f, 0.f, 0.f};
  f32x4 acc[4][4];
#pragma unroll
  for (int i = 0; i < 4; ++i)
#pragma unroll
    for (int j = 0; j < 4; ++j) acc[i][j] = zero;

  const float* gA = X + (size_t)(m0 + srow) * HID + shalf * 32;
  const float* gB = W + (size_t)(n0 + srow) * HID + shalf * 32;

  for (int k0 = 0; k0 < HID; k0 += 64) {
#pragma unroll
    for (int i = 0; i < 4; ++i) {
      float4 a0 = ((const float4*)(gA + k0))[2 * i];
      float4 a1 = ((const float4*)(gA + k0))[2 * i + 1];
      u16x8 pa;
      pa[0] = f2b(a0.x); pa[1] = f2b(a0.y); pa[2] = f2b(a0.z); pa[3] = f2b(a0.w);
      pa[4] = f2b(a1.x); pa[5] = f2b(a1.y); pa[6] = f2b(a1.z); pa[7] = f2b(a1.w);
      *(u16x8*)&lA[srow][shalf * 32 + i * 8] = pa;
      float4 b0 = ((const float4*)(gB + k0))[2 * i];
      float4 b1 = ((const float4*)(gB + k0))[2 * i + 1];
      u16x8 pb;
      pb[0] = f2b(b0.x); pb[1] = f2b(b0.y); pb[2] = f2b(b0.z); pb[3] = f2b(b0.w);
      pb[4] = f2b(b1.x); pb[5] = f2b(b1.y); pb[6] = f2b(b1.z); pb[7] = f2b(b1.w);
      *(u16x8*)&lB[srow][shalf * 32 + i * 8] = pb;
    }
    __syncthreads();
#pragma unroll
    for (int kk = 0; kk < 2; ++kk) {
      s16x8 af[4], bfr[4];
#pragma unroll
      for (int i = 0; i < 4; ++i)
        af[i] = *(const s16x8*)&lA[wm * 64 + i * 16 + lr][kk * 32 + lg * 8];
#pragma unroll
      for (int j = 0; j < 4; ++j)
        bfr[j] = *(const s16x8*)&lB[wn * 64 + j * 16 + lr][kk * 32 + lg * 8];
#pragma unroll
      for (int i = 0; i < 4; ++i)
#pragma unroll
        for (int j = 0; j < 4; ++j)
          acc[i][j] = __builtin_amdgcn_mfma_f32_16x16x32_bf16(af[i], bfr[j], acc[i][j], 0, 0, 0);
    }
    __syncthreads();
  }

#pragma unroll
  for (int i = 0; i < 4; ++i) {
#pragma unroll
    for (int j = 0; j < 4; ++j) {
      const int n = n0 + wn * 64 + j * 16 + lr;
      const float bv = bias[n];
#pragma unroll
      for (int r = 0; r < 4; ++r) {
        const int m = m0 + wm * 64 + i * 16 + lg * 4 + r;
        C[(size_t)m * HID + n] = __float2bfloat16(acc[i][j][r] + bv);
      }
    }
  }
}

// ---------------------------------------------------------------------------
// Final batched GEMM: out[b] = MQ[b] @ (Wt * pk[b])^T + bt + MQ[b]   (fp32 out)
// ---------------------------------------------------------------------------
__global__ __launch_bounds__(256) void gemm_final_kernel(
    const __hip_bfloat16* __restrict__ MQ,  // [B,S,HID] bf16
    const float* __restrict__ Wt,           // [HID,HID]
    const float* __restrict__ pk,           // [B,HID]
    const float* __restrict__ bt,           // [HID]
    float* __restrict__ out)                // [B,S,HID]
{
  __shared__ unsigned short lA[128][72];
  __shared__ unsigned short lB[128][72];

  const int b = blockIdx.z;
  const unsigned short* A = (const unsigned short*)MQ + (size_t)b * S * HID;
  float* C = out + (size_t)b * S * HID;
  const float* gate = pk + b * HID;

  const int m0 = blockIdx.x * 128;
  const int n0 = blockIdx.y * 128;

  const int t = threadIdx.x;
  const int srow = t >> 1, shalf = t & 1;
  const int lane = t & 63, wv = t >> 6;
  const int wm = wv >> 1, wn = wv & 1;
  const int lg = lane >> 4, lr = lane & 15;

  const f32x4 zero = {0.f, 0.f, 0.f, 0.f};
  f32x4 acc[4][4];
#pragma unroll
  for (int i = 0; i < 4; ++i)
#pragma unroll
    for (int j = 0; j < 4; ++j) acc[i][j] = zero;

  const unsigned short* gA = A + (size_t)(m0 + srow) * HID + shalf * 32;
  const float* gB = Wt + (size_t)(n0 + srow) * HID + shalf * 32;
  const float* gG = gate + shalf * 32;

  for (int k0 = 0; k0 < HID; k0 += 64) {
#pragma unroll
    for (int i = 0; i < 4; ++i) {
      u16x8 va = ((const u16x8*)(gA + k0))[i];
      *(u16x8*)&lA[srow][shalf * 32 + i * 8] = va;
      float4 b0 = ((const float4*)(gB + k0))[2 * i];
      float4 b1 = ((const float4*)(gB + k0))[2 * i + 1];
      float4 g0 = ((const float4*)(gG + k0))[2 * i];
      float4 g1 = ((const float4*)(gG + k0))[2 * i + 1];
      u16x8 pb;
      pb[0] = f2b(b0.x * g0.x); pb[1] = f2b(b0.y * g0.y);
      pb[2] = f2b(b0.z * g0.z); pb[3] = f2b(b0.w * g0.w);
      pb[4] = f2b(b1.x * g1.x); pb[5] = f2b(b1.y * g1.y);
      pb[6] = f2b(b1.z * g1.z); pb[7] = f2b(b1.w * g1.w);
      *(u16x8*)&lB[srow][shalf * 32 + i * 8] = pb;
    }
    __syncthreads();
#pragma unroll
    for (int kk = 0; kk < 2; ++kk) {
      s16x8 af[4], bfr[4];
#pragma unroll
      for (int i = 0; i < 4; ++i)
        af[i] = *(const s16x8*)&lA[wm * 64 + i * 16 + lr][kk * 32 + lg * 8];
#pragma unroll
      for (int j = 0; j < 4; ++j)
        bfr[j] = *(const s16x8*)&lB[wn * 64 + j * 16 + lr][kk * 32 + lg * 8];
#pragma unroll
      for (int i = 0; i < 4; ++i)
#pragma unroll
        for (int j = 0; j < 4; ++j)
          acc[i][j] = __builtin_amdgcn_mfma_f32_16x16x32_bf16(af[i], bfr[j], acc[i][j], 0, 0, 0);
    }
    __syncthreads();
  }

#pragma unroll
  for (int i = 0; i < 4; ++i) {
#pragma unroll
    for (int j = 0; j < 4; ++j) {
      const int n = n0 + wn * 64 + j * 16 + lr;
      const float bv = bt[n];
#pragma unroll
      for (int r = 0; r < 4; ++r) {
        const int m = m0 + wm * 64 + i * 16 + lg * 4 + r;
        C[(size_t)m * HID + n] = acc[i][j][r] + bv + bf2f(A[(size_t)m * HID + n]);
      }
    }
  }
}

// ---------------------------------------------------------------------------
// scores[b,h,s] = (sum_c MX[b,s,c] * Wa[(b?)..,h,c] + ba[h]) * SCALE + mask[b,s]
// One wave per (b,s) row; lane: h = lane&15, quarter q = lane>>4.
// ---------------------------------------------------------------------------
__global__ __launch_bounds__(256) void score_kernel(
    const __hip_bfloat16* __restrict__ MX,  // [B*S, HID] bf16
    const float* __restrict__ Wa,           // [16,HID] or [B,16,HID]
    const float* __restrict__ ba,           // [16]
    const float* __restrict__ mask,         // [B,S]
    float* __restrict__ scores,             // [B,16,S]
    int wBatchStride)                       // 0 or 16*HID
{
  const int t = threadIdx.x;
  const int wv = t >> 6, lane = t & 63;
  const int row = blockIdx.x * 4 + wv;  // [0, 32768)
  const int b = row >> 12, s = row & 4095;
  const int h = lane & 15, q = lane >> 4;

  const unsigned short* xr = (const unsigned short*)MX + (size_t)row * HID + q * 256;
  const float* wr = Wa + (size_t)b * wBatchStride + h * HID + q * 256;

  float sum = 0.f;
#pragma unroll 4
  for (int c = 0; c < 256; c += 8) {
    u16x8 xv = *(const u16x8*)(xr + c);
    float4 w0 = *(const float4*)(wr + c);
    float4 w1 = *(const float4*)(wr + c + 4);
    sum += bf2f(xv[0]) * w0.x + bf2f(xv[1]) * w0.y + bf2f(xv[2]) * w0.z + bf2f(xv[3]) * w0.w;
    sum += bf2f(xv[4]) * w1.x + bf2f(xv[5]) * w1.y + bf2f(xv[6]) * w1.z + bf2f(xv[7]) * w1.w;
  }
  sum += __shfl_xor(sum, 16);
  sum += __shfl_xor(sum, 32);
  if (lane < 16) {
    scores[((size_t)b * 16 + h) * S + s] = (sum + ba[h]) * SCALE + mask[(size_t)b * S + s];
  }
}

// ---------------------------------------------------------------------------
// Per (b,h): softmax over scores[b,h,:], then pooled[b,h*64+d] =
//   (sum_s w_s * MX[b,s,h*64+d]) / denom   (* pq gate if GATE)
// ---------------------------------------------------------------------------
template <bool GATE>
__global__ __launch_bounds__(256) void softmax_pool_kernel(
    const float* __restrict__ scores,       // [B,16,S]
    const __hip_bfloat16* __restrict__ MX,  // [B,S,HID]
    const float* __restrict__ pq,           // [B,HID] gate (GATE only)
    float* __restrict__ pooled)             // [B,HID]
{
  __shared__ float w[S];
  __shared__ float red[8];
  __shared__ float rb[8][64];

  const int bh = blockIdx.x;  // [0,128)
  const int b = bh >> 4, h = bh & 15;
  const float* sc = scores + (size_t)bh * S;
  const int t = threadIdx.x;
  const int lane = t & 63, wv = t >> 6;

  float m = -3.4e38f;
  for (int i = t; i < S; i += 256) { float v = sc[i]; w[i] = v; m = fmaxf(m, v); }
#pragma unroll
  for (int o = 1; o < 64; o <<= 1) m = fmaxf(m, __shfl_xor(m, o));
  if (lane == 0) red[wv] = m;
  __syncthreads();
  const float gmax = fmaxf(fmaxf(red[0], red[1]), fmaxf(red[2], red[3]));
  float sum = 0.f;
  for (int i = t; i < S; i += 256) { float e = __expf(w[i] - gmax); w[i] = e; sum += e; }
#pragma unroll
  for (int o = 1; o < 64; o <<= 1) sum += __shfl_xor(sum, o);
  if (lane == 0) red[4 + wv] = sum;
  __syncthreads();
  const float inv = 1.0f / (red[4] + red[5] + red[6] + red[7]);

  const int dp = (t & 31) * 2, sg = t >> 5;  // 8 s-groups, 32 d-pairs
  const unsigned short* base =
      (const unsigned short*)MX + (size_t)b * S * HID + h * HD + dp;
  float a0 = 0.f, a1 = 0.f;
  for (int s = sg; s < S; s += 8) {
    const float ww = w[s];
    const unsigned int xv = *(const unsigned int*)(base + (size_t)s * HID);
    a0 += ww * bf2f((unsigned short)(xv & 0xffffu));
    a1 += ww * bf2f((unsigned short)(xv >> 16));
  }
  rb[sg][dp] = a0; rb[sg][dp + 1] = a1;
  __syncthreads();
  if (t < 64) {
    float r = 0.f;
#pragma unroll
    for (int g = 0; g < 8; ++g) r += rb[g][t];
    r *= inv;
    if (GATE) r *= pq[(size_t)b * HID + h * HD + t];
    pooled[(size_t)b * HID + h * HD + t] = r;
  }
}

// Wka_eff[b,h,c] = Wka[h,c] * pq[b,c]
__global__ __launch_bounds__(256) void fold_wka_kernel(
    const float* __restrict__ Wka, const float* __restrict__ pq,
    float* __restrict__ out)
{
  const int i = blockIdx.x * 256 + threadIdx.x;  // < 8*16*1024
  const int b = i >> 14, c = i & 1023, hc = i & 16383;
  out[i] = Wka[hc] * pq[b * HID + c];
}

// ---------------------------------------------------------------------------
extern "C" void kernel_launch(void* const* d_in, const int* in_sizes, int n_in,
                              void* d_out, int out_size, void* d_ws, size_t ws_size,
                              hipStream_t stream) {
  const float* X    = (const float*)d_in[0];
  const float* mask = (const float*)d_in[1];
  const float* Wq   = (const float*)d_in[2];
  const float* bq   = (const float*)d_in[3];
  const float* Wqa  = (const float*)d_in[4];
  const float* bqa  = (const float*)d_in[5];
  const float* Wk   = (const float*)d_in[6];
  const float* bk   = (const float*)d_in[7];
  const float* Wka  = (const float*)d_in[8];
  const float* bka  = (const float*)d_in[9];
  const float* Wt   = (const float*)d_in[10];
  const float* bt   = (const float*)d_in[11];
  float* out = (float*)d_out;

  char* ws = (char*)d_ws;
  __hip_bfloat16* MQ = (__hip_bfloat16*)ws;  ws += (size_t)MTOT * HID * 2;
  __hip_bfloat16* MK = (__hip_bfloat16*)ws;  ws += (size_t)MTOT * HID * 2;
  float* qs      = (float*)ws;  ws += (size_t)BATCH * NH * S * 4;
  float* pq      = (float*)ws;  ws += (size_t)BATCH * HID * 4;
  float* pk      = (float*)ws;  ws += (size_t)BATCH * HID * 4;
  float* Wka_eff = (float*)ws;  ws += (size_t)BATCH * NH * HID * 4;

  // 1. MQ, MK
  gemm_dual_kernel<<<dim3(MTOT / 128, 16), 256, 0, stream>>>(X, Wq, Wk, bq, bk, MQ, MK);
  // 2. q scores
  score_kernel<<<dim3(MTOT / 4), 256, 0, stream>>>(MQ, Wqa, bqa, mask, qs, 0);
  // 3. softmax + pool -> pooled_q
  softmax_pool_kernel<false><<<dim3(BATCH * NH), 256, 0, stream>>>(qs, MQ, nullptr, pq);
  // 4. fold pq into Wka
  fold_wka_kernel<<<dim3(BATCH * NH * HID / 256), 256, 0, stream>>>(Wka, pq, Wka_eff);
  // 5. qk scores
  score_kernel<<<dim3(MTOT / 4), 256, 0, stream>>>(MK, Wka_eff, bka, mask, qs, NH * HID);
  // 6. softmax + pool (gated) -> pooled_k
  softmax_pool_kernel<true><<<dim3(BATCH * NH), 256, 0, stream>>>(qs, MK, pq, pk);
  // 7. out = MQ @ (Wt*pk)^T + bt + MQ
  gemm_final_kernel<<<dim3(S / 128, HID / 128, BATCH), 256, 0, stream>>>(MQ, Wt, pk, bt, out);
}

// Round 3
// 923.530 us; speedup vs baseline: 2.0555x; 2.0555x over previous
//
#include <hip/hip_runtime.h>
#include <hip/hip_bf16.h>
#include <cstdint>
#include <cstddef>

typedef unsigned short u16;
typedef __attribute__((ext_vector_type(8))) short s16x8;
typedef __attribute__((ext_vector_type(8))) unsigned short u16x8;
typedef __attribute__((ext_vector_type(4))) unsigned short u16x4;
typedef __attribute__((ext_vector_type(4))) float f32x4;

#define DEVI static __device__ __forceinline__

constexpr int S = 4096, HID = 1024, NH = 16, HD = 64, BATCH = 8;
constexpr int MTOT = BATCH * S;  // 32768
constexpr float SCALE = 0.125f;  // 1/sqrt(64)

DEVI float bf2f(u16 u) {
  union { unsigned int i; float f; } v; v.i = ((unsigned int)u) << 16; return v.f;
}
DEVI u16 f2b(float f) {
  __hip_bfloat16 h = __float2bfloat16(f);
  return *reinterpret_cast<u16*>(&h);
}

// global -> LDS async copy, 16B per lane. LDS dest must be wave-uniform;
// HW scatters lane i at ldst + i*16.
DEVI void gld16(const u16* g, u16* ldst) {
  __builtin_amdgcn_global_load_lds(
      (const __attribute__((address_space(1))) unsigned int*)g,
      (__attribute__((address_space(3))) unsigned int*)ldst, 16, 0, 0);
}

// ---------------------------------------------------------------------------
// fp32 -> bf16 convert, 8 elems/thread
// ---------------------------------------------------------------------------
__global__ __launch_bounds__(256) void conv_bf16_kernel(
    const float* __restrict__ in, u16* __restrict__ out, int n)
{
  const size_t i = ((size_t)blockIdx.x * 256 + threadIdx.x) * 8;
  if (i >= (size_t)n) return;
  float4 a = *(const float4*)(in + i);
  float4 b = *(const float4*)(in + i + 4);
  u16x8 o;
  o[0] = f2b(a.x); o[1] = f2b(a.y); o[2] = f2b(a.z); o[3] = f2b(a.w);
  o[4] = f2b(b.x); o[5] = f2b(b.y); o[6] = f2b(b.z); o[7] = f2b(b.w);
  *(u16x8*)(out + i) = o;
}

// ---------------------------------------------------------------------------
// m97-structure bf16 GEMM: MQ = Xb @ Wqb^T + bq  (bf16 out)
// A [32768,1024], B [1024,1024] (row = n), tile 128x128, BK=64, 256 thr.
// ---------------------------------------------------------------------------
__global__ __launch_bounds__(256) void gemm_mq_kernel(
    const u16* __restrict__ A, const u16* __restrict__ B,
    const float* __restrict__ bias, u16* __restrict__ C)
{
  __shared__ u16 lA[128 * 64];
  __shared__ u16 lB[128 * 64];
  const int m0 = blockIdx.x * 128, n0 = blockIdx.y * 128;
  const int t = threadIdx.x, lane = t & 63, wv = t >> 6;
  const int wm = wv >> 1, wn = wv & 1, lg = lane >> 4, lr = lane & 15;

  const f32x4 zero = {0.f, 0.f, 0.f, 0.f};
  f32x4 acc[4][4];
#pragma unroll
  for (int i = 0; i < 4; ++i)
#pragma unroll
    for (int j = 0; j < 4; ++j) acc[i][j] = zero;

  const u16* gA = A + (size_t)m0 * HID;
  const u16* gB = B + (size_t)n0 * HID;

  for (int k0 = 0; k0 < HID; k0 += 64) {
#pragma unroll
    for (int i = 0; i < 4; ++i) {
      const int c = i * 256 + t;          // chunk: row=c>>3, col=(c&7)*8
      gld16(gA + (size_t)(c >> 3) * HID + k0 + (c & 7) * 8, lA + i * 2048 + wv * 512);
      gld16(gB + (size_t)(c >> 3) * HID + k0 + (c & 7) * 8, lB + i * 2048 + wv * 512);
    }
    __syncthreads();
#pragma unroll
    for (int kk = 0; kk < 2; ++kk) {
      s16x8 af[4], bfv[4];
#pragma unroll
      for (int i = 0; i < 4; ++i)
        af[i] = *(const s16x8*)&lA[(wm * 64 + i * 16 + lr) * 64 + kk * 32 + lg * 8];
#pragma unroll
      for (int j = 0; j < 4; ++j)
        bfv[j] = *(const s16x8*)&lB[(wn * 64 + j * 16 + lr) * 64 + kk * 32 + lg * 8];
#pragma unroll
      for (int i = 0; i < 4; ++i)
#pragma unroll
        for (int j = 0; j < 4; ++j)
          acc[i][j] = __builtin_amdgcn_mfma_f32_16x16x32_bf16(af[i], bfv[j], acc[i][j], 0, 0, 0);
    }
    __syncthreads();
  }

#pragma unroll
  for (int i = 0; i < 4; ++i)
#pragma unroll
    for (int j = 0; j < 4; ++j) {
      const int n = n0 + wn * 64 + j * 16 + lr;
      const float bv = bias[n];
#pragma unroll
      for (int r = 0; r < 4; ++r) {
        const int m = m0 + wm * 64 + i * 16 + lg * 4 + r;
        C[(size_t)m * HID + n] = f2b(acc[i][j][r] + bv);
      }
    }
}

// ---------------------------------------------------------------------------
// Final GEMM: out = MQ @ WtE[b]^T + bt + fp32(MQ)   (fp32 out)
// ---------------------------------------------------------------------------
__global__ __launch_bounds__(256) void gemm_final_kernel(
    const u16* __restrict__ A, const u16* __restrict__ WtE,
    const float* __restrict__ bt, float* __restrict__ out)
{
  __shared__ u16 lA[128 * 64];
  __shared__ u16 lB[128 * 64];
  const int m0 = blockIdx.x * 128, n0 = blockIdx.y * 128;
  const int b = m0 >> 12;
  const u16* B = WtE + (size_t)b * HID * HID;
  const int t = threadIdx.x, lane = t & 63, wv = t >> 6;
  const int wm = wv >> 1, wn = wv & 1, lg = lane >> 4, lr = lane & 15;

  const f32x4 zero = {0.f, 0.f, 0.f, 0.f};
  f32x4 acc[4][4];
#pragma unroll
  for (int i = 0; i < 4; ++i)
#pragma unroll
    for (int j = 0; j < 4; ++j) acc[i][j] = zero;

  const u16* gA = A + (size_t)m0 * HID;
  const u16* gB = B + (size_t)n0 * HID;

  for (int k0 = 0; k0 < HID; k0 += 64) {
#pragma unroll
    for (int i = 0; i < 4; ++i) {
      const int c = i * 256 + t;
      gld16(gA + (size_t)(c >> 3) * HID + k0 + (c & 7) * 8, lA + i * 2048 + wv * 512);
      gld16(gB + (size_t)(c >> 3) * HID + k0 + (c & 7) * 8, lB + i * 2048 + wv * 512);
    }
    __syncthreads();
#pragma unroll
    for (int kk = 0; kk < 2; ++kk) {
      s16x8 af[4], bfv[4];
#pragma unroll
      for (int i = 0; i < 4; ++i)
        af[i] = *(const s16x8*)&lA[(wm * 64 + i * 16 + lr) * 64 + kk * 32 + lg * 8];
#pragma unroll
      for (int j = 0; j < 4; ++j)
        bfv[j] = *(const s16x8*)&lB[(wn * 64 + j * 16 + lr) * 64 + kk * 32 + lg * 8];
#pragma unroll
      for (int i = 0; i < 4; ++i)
#pragma unroll
        for (int j = 0; j < 4; ++j)
          acc[i][j] = __builtin_amdgcn_mfma_f32_16x16x32_bf16(af[i], bfv[j], acc[i][j], 0, 0, 0);
    }
    __syncthreads();
  }

#pragma unroll
  for (int i = 0; i < 4; ++i)
#pragma unroll
    for (int j = 0; j < 4; ++j) {
      const int n = n0 + wn * 64 + j * 16 + lr;
      const float bv = bt[n];
#pragma unroll
      for (int r = 0; r < 4; ++r) {
        const int m = m0 + wm * 64 + i * 16 + lg * 4 + r;
        out[(size_t)m * HID + n] = acc[i][j][r] + bv + bf2f(A[(size_t)m * HID + n]);
      }
    }
}

// ---------------------------------------------------------------------------
// Skinny score GEMM via MFMA: scores[b,h,s] = (A[m,:]·Bw[h,:] + bias)*SCALE + mask
// A bf16 [32768,1024]; Bw bf16 [16,1024] (+ b*bstride). N=16 -> 1 frag.
// M-tile 128, 4 waves, each wave 2 m-frags.
// ---------------------------------------------------------------------------
__global__ __launch_bounds__(256) void score_mfma_kernel(
    const u16* __restrict__ A, const u16* __restrict__ Bw,
    const float* __restrict__ bias, const float* __restrict__ mask,
    float* __restrict__ scores, int bstride, int biasBH)
{
  __shared__ u16 lA[128 * 64];
  const int m0 = blockIdx.x * 128;
  const int b = m0 >> 12;
  const u16* B = Bw + (size_t)b * bstride;
  const int t = threadIdx.x, lane = t & 63, wv = t >> 6;
  const int lg = lane >> 4, lr = lane & 15;

  f32x4 acc0 = {0.f, 0.f, 0.f, 0.f}, acc1 = {0.f, 0.f, 0.f, 0.f};

  for (int k0 = 0; k0 < HID; k0 += 64) {
#pragma unroll
    for (int i = 0; i < 4; ++i) {
      const int c = i * 256 + t;
      gld16(A + (size_t)(m0 + (c >> 3)) * HID + k0 + (c & 7) * 8, lA + i * 2048 + wv * 512);
    }
    __syncthreads();
#pragma unroll
    for (int kk = 0; kk < 2; ++kk) {
      s16x8 bf = *(const s16x8*)(B + lr * HID + k0 + kk * 32 + lg * 8);
      s16x8 a0 = *(const s16x8*)&lA[(wv * 32 + lr) * 64 + kk * 32 + lg * 8];
      s16x8 a1 = *(const s16x8*)&lA[(wv * 32 + 16 + lr) * 64 + kk * 32 + lg * 8];
      acc0 = __builtin_amdgcn_mfma_f32_16x16x32_bf16(a0, bf, acc0, 0, 0, 0);
      acc1 = __builtin_amdgcn_mfma_f32_16x16x32_bf16(a1, bf, acc1, 0, 0, 0);
    }
    __syncthreads();
  }

  const int h = lr;
  const float bv = biasBH ? bias[b * 16 + h] : bias[h];
#pragma unroll
  for (int i = 0; i < 2; ++i) {
    f32x4 a = i ? acc1 : acc0;
#pragma unroll
    for (int r = 0; r < 4; ++r) {
      const int m = m0 + wv * 32 + i * 16 + lg * 4 + r;
      const int s = m & 4095;
      scores[((size_t)b * 16 + h) * S + s] = (a[r] + bv) * SCALE + mask[m];
    }
  }
}

// ---------------------------------------------------------------------------
// Per (b,h): softmax over scores row; pooled[b,h*64+d] = sum_s w_s*MX[b,s,h*64+d]
// ---------------------------------------------------------------------------
__global__ __launch_bounds__(256) void softmax_pool_kernel(
    const float* __restrict__ scores, const u16* __restrict__ MX,
    float* __restrict__ pooled)
{
  __shared__ float w[S];
  __shared__ float red[8];
  __shared__ float rb[8][64];

  const int bh = blockIdx.x;
  const int b = bh >> 4, h = bh & 15;
  const float* sc = scores + (size_t)bh * S;
  const int t = threadIdx.x, lane = t & 63, wv = t >> 6;

  float m = -3.4e38f;
  for (int i = t; i < S; i += 256) { float v = sc[i]; w[i] = v; m = fmaxf(m, v); }
#pragma unroll
  for (int o = 1; o < 64; o <<= 1) m = fmaxf(m, __shfl_xor(m, o));
  if (lane == 0) red[wv] = m;
  __syncthreads();
  const float gmax = fmaxf(fmaxf(red[0], red[1]), fmaxf(red[2], red[3]));
  float sum = 0.f;
  for (int i = t; i < S; i += 256) { float e = __expf(w[i] - gmax); w[i] = e; sum += e; }
#pragma unroll
  for (int o = 1; o < 64; o <<= 1) sum += __shfl_xor(sum, o);
  if (lane == 0) red[4 + wv] = sum;
  __syncthreads();
  const float inv = 1.0f / (red[4] + red[5] + red[6] + red[7]);

  const int dp = (t & 31) * 2, sg = t >> 5;
  const u16* base = MX + (size_t)b * S * HID + h * HD + dp;
  float a0 = 0.f, a1 = 0.f;
#pragma unroll 4
  for (int s = sg; s < S; s += 8) {
    const float ww = w[s];
    const unsigned int xv = *(const unsigned int*)(base + (size_t)s * HID);
    a0 += ww * bf2f((u16)(xv & 0xffffu));
    a1 += ww * bf2f((u16)(xv >> 16));
  }
  rb[sg][dp] = a0; rb[sg][dp + 1] = a1;
  __syncthreads();
  if (t < 64) {
    float r = 0.f;
#pragma unroll
    for (int g = 0; g < 8; ++g) r += rb[g][t];
    pooled[(size_t)b * HID + h * HD + t] = r * inv;
  }
}

// WkaE[b,h,c] = Wka[h,c] * pq[b,c]   (fp32)
__global__ __launch_bounds__(256) void fold_wka_kernel(
    const float* __restrict__ Wka, const float* __restrict__ pq,
    float* __restrict__ out)
{
  const int i = blockIdx.x * 256 + threadIdx.x;  // < 8*16*1024
  const int b = i >> 14, c = i & 1023, hc = i & 16383;
  out[i] = Wka[hc] * pq[b * HID + c];
}

// biask[b*16+h] = bka[h] + sum_c WkaE[b,h,c]*bk[c]
__global__ __launch_bounds__(64) void delta_kernel(
    const float* __restrict__ WkaE, const float* __restrict__ bk,
    const float* __restrict__ bka, float* __restrict__ biask)
{
  const int bh = blockIdx.x;
  const float* wr = WkaE + (size_t)bh * HID;
  float s = 0.f;
  for (int i = threadIdx.x; i < HID; i += 64) s += wr[i] * bk[i];
#pragma unroll
  for (int o = 1; o < 64; o <<= 1) s += __shfl_xor(s, o);
  if (threadIdx.x == 0) biask[bh] = bka[bh & 15] + s;
}

// vb[b,h,c'] = bf16( sum_c WkaE[b,h,c] * Wk[c,c'] )
__global__ __launch_bounds__(256) void v_kernel(
    const float* __restrict__ WkaE, const float* __restrict__ Wk,
    u16* __restrict__ vb)
{
  const int b = blockIdx.x;
  const int cp = blockIdx.y * 256 + threadIdx.x;
  const float* wka = WkaE + (size_t)b * NH * HID;
  float acc[16];
#pragma unroll
  for (int h = 0; h < 16; ++h) acc[h] = 0.f;
  for (int c = 0; c < HID; ++c) {
    const float wkc = Wk[(size_t)c * HID + cp];
#pragma unroll
    for (int h = 0; h < 16; ++h) acc[h] += wka[h * HID + c] * wkc;
  }
#pragma unroll
  for (int h = 0; h < 16; ++h) vb[((size_t)b * 16 + h) * HID + cp] = f2b(acc[h]);
}

// per (b,h): gmax and 1/sum(exp) over scores row
__global__ __launch_bounds__(256) void softmax_stats_kernel(
    const float* __restrict__ scores, float* __restrict__ stats)
{
  __shared__ float red[8];
  const int bh = blockIdx.x;
  const float* sc = scores + (size_t)bh * S;
  const int t = threadIdx.x, lane = t & 63, wv = t >> 6;
  float m = -3.4e38f;
  for (int i = t; i < S; i += 256) m = fmaxf(m, sc[i]);
#pragma unroll
  for (int o = 1; o < 64; o <<= 1) m = fmaxf(m, __shfl_xor(m, o));
  if (lane == 0) red[wv] = m;
  __syncthreads();
  const float gmax = fmaxf(fmaxf(red[0], red[1]), fmaxf(red[2], red[3]));
  float s = 0.f;
  for (int i = t; i < S; i += 256) s += __expf(sc[i] - gmax);
#pragma unroll
  for (int o = 1; o < 64; o <<= 1) s += __shfl_xor(s, o);
  if (lane == 0) red[4 + wv] = s;
  __syncthreads();
  if (t == 0) {
    stats[bh * 2] = gmax;
    stats[bh * 2 + 1] = 1.0f / (red[4] + red[5] + red[6] + red[7]);
  }
}

// t[b,h,c'] += sum_{s in chunk} w[b,h,s] * X[b,s,c']  (atomic accumulate)
__global__ __launch_bounds__(256) void pool_k_partial_kernel(
    const float* __restrict__ scores, const float* __restrict__ stats,
    const u16* __restrict__ Xb, float* __restrict__ tacc)
{
  __shared__ float wl[16 * 256];
  const int b = blockIdx.x, sc0 = blockIdx.y * 256;
  const int t = threadIdx.x;
#pragma unroll
  for (int j = 0; j < 16; ++j) {
    const int idx = j * 256 + t;           // 0..4095
    const int h = idx >> 8, sl = idx & 255;
    const float g = stats[(b * 16 + h) * 2], inv = stats[(b * 16 + h) * 2 + 1];
    wl[h * 256 + sl] = __expf(scores[((size_t)b * 16 + h) * S + sc0 + sl] - g) * inv;
  }
  __syncthreads();

  float acc[16][4];
#pragma unroll
  for (int h = 0; h < 16; ++h)
#pragma unroll
    for (int j = 0; j < 4; ++j) acc[h][j] = 0.f;

  const u16* xp = Xb + ((size_t)(b * S + sc0)) * HID + t * 4;
  for (int sl = 0; sl < 256; ++sl) {
    u16x4 xv = *(const u16x4*)(xp + (size_t)sl * HID);
    const float x0 = bf2f(xv[0]), x1 = bf2f(xv[1]), x2 = bf2f(xv[2]), x3 = bf2f(xv[3]);
#pragma unroll
    for (int h = 0; h < 16; ++h) {
      const float ww = wl[h * 256 + sl];
      acc[h][0] += ww * x0; acc[h][1] += ww * x1;
      acc[h][2] += ww * x2; acc[h][3] += ww * x3;
    }
  }
#pragma unroll
  for (int h = 0; h < 16; ++h)
#pragma unroll
    for (int j = 0; j < 4; ++j)
      atomicAdd(&tacc[((size_t)b * 16 + h) * HID + t * 4 + j], acc[h][j]);
}

// pk[b,hd] = (t[b,h,:]·Wk[hd,:] + bk[hd]) * pq[b,hd]
__global__ __launch_bounds__(256) void finalize_pk_kernel(
    const float* __restrict__ tacc, const float* __restrict__ Wk,
    const float* __restrict__ bk, const float* __restrict__ pq,
    float* __restrict__ pk)
{
  __shared__ float ts[HID];
  const int b = blockIdx.x, h = blockIdx.y;
  const int t = threadIdx.x;
  const float* trow = tacc + ((size_t)b * 16 + h) * HID;
  for (int i = t; i < HID; i += 256) ts[i] = trow[i];
  __syncthreads();
  const int d = t >> 2, part = t & 3;
  const float* wrow = Wk + (size_t)(h * 64 + d) * HID + part * 256;
  float s = 0.f;
#pragma unroll 4
  for (int i = 0; i < 256; i += 4) {
    float4 w4 = *(const float4*)(wrow + i);
    s += ts[part * 256 + i] * w4.x + ts[part * 256 + i + 1] * w4.y +
         ts[part * 256 + i + 2] * w4.z + ts[part * 256 + i + 3] * w4.w;
  }
  s += __shfl_xor(s, 1);
  s += __shfl_xor(s, 2);
  if (part == 0) {
    const int hd = h * 64 + d;
    pk[b * HID + hd] = (s + bk[hd]) * pq[b * HID + hd];
  }
}

// WtE[b,n,c] = bf16(Wt[n,c] * pk[b,c])
__global__ __launch_bounds__(256) void fold_wt_kernel(
    const float* __restrict__ Wt, const float* __restrict__ pk,
    u16* __restrict__ WtE)
{
  const size_t j = ((size_t)blockIdx.x * 256 + threadIdx.x) * 4;  // < 8*1M
  const int b = (int)(j >> 20);
  const size_t r = j & 1048575;
  const int c = (int)(j & 1023);
  float4 w = *(const float4*)(Wt + r);
  float4 g = *(const float4*)(pk + b * HID + c);
  u16x4 o;
  o[0] = f2b(w.x * g.x); o[1] = f2b(w.y * g.y);
  o[2] = f2b(w.z * g.z); o[3] = f2b(w.w * g.w);
  *(u16x4*)(WtE + (size_t)b * HID * HID + r) = o;
}

// ---------------------------------------------------------------------------
extern "C" void kernel_launch(void* const* d_in, const int* in_sizes, int n_in,
                              void* d_out, int out_size, void* d_ws, size_t ws_size,
                              hipStream_t stream) {
  const float* X    = (const float*)d_in[0];
  const float* mask = (const float*)d_in[1];
  const float* Wq   = (const float*)d_in[2];
  const float* bq   = (const float*)d_in[3];
  const float* Wqa  = (const float*)d_in[4];
  const float* bqa  = (const float*)d_in[5];
  const float* Wk   = (const float*)d_in[6];
  const float* bk   = (const float*)d_in[7];
  const float* Wka  = (const float*)d_in[8];
  const float* bka  = (const float*)d_in[9];
  const float* Wt   = (const float*)d_in[10];
  const float* bt   = (const float*)d_in[11];
  float* out = (float*)d_out;

  // Xb (bf16 X) lives in d_out: dead before gemm_final writes out.
  u16* Xb = (u16*)d_out;

  char* ws = (char*)d_ws;
  u16* MQ     = (u16*)ws;   ws += (size_t)MTOT * HID * 2;       // 67.1MB
  u16* Wqb    = (u16*)ws;   ws += (size_t)HID * HID * 2;        // 2MB
  u16* Wqab   = (u16*)ws;   ws += (size_t)NH * HID * 2;         // 32KB
  u16* vb     = (u16*)ws;   ws += (size_t)BATCH * NH * HID * 2; // 256KB
  u16* WtE    = (u16*)ws;   ws += (size_t)BATCH * HID * HID * 2;// 16.8MB
  float* qs   = (float*)ws; ws += (size_t)BATCH * NH * S * 4;   // 2MB
  float* pq   = (float*)ws; ws += (size_t)BATCH * HID * 4;
  float* pk   = (float*)ws; ws += (size_t)BATCH * HID * 4;
  float* WkaE = (float*)ws; ws += (size_t)BATCH * NH * HID * 4; // 512KB
  float* tacc = (float*)ws; ws += (size_t)BATCH * NH * HID * 4; // 512KB
  float* stats= (float*)ws; ws += (size_t)BATCH * NH * 2 * 4;
  float* biask= (float*)ws; ws += (size_t)BATCH * NH * 4;

  // zero the atomic accumulator
  hipMemsetAsync(tacc, 0, (size_t)BATCH * NH * HID * 4, stream);

  // 1. convert to bf16
  conv_bf16_kernel<<<dim3(MTOT * HID / 2048), 256, 0, stream>>>(X, Xb, MTOT * HID);
  conv_bf16_kernel<<<dim3(HID * HID / 2048), 256, 0, stream>>>(Wq, Wqb, HID * HID);
  conv_bf16_kernel<<<dim3(NH * HID / 2048), 256, 0, stream>>>(Wqa, Wqab, NH * HID);

  // 2. MQ = Xb@Wqb^T + bq
  gemm_mq_kernel<<<dim3(MTOT / 128, HID / 128), 256, 0, stream>>>(Xb, Wqb, bq, MQ);

  // 3. q scores
  score_mfma_kernel<<<dim3(MTOT / 128), 256, 0, stream>>>(MQ, Wqab, bqa, mask, qs, 0, 0);

  // 4. softmax+pool -> pq
  softmax_pool_kernel<<<dim3(BATCH * NH), 256, 0, stream>>>(qs, MQ, pq);

  // 5. WkaE = Wka ⊙ pq ; folded k-bias ; v = WkaE @ Wk
  fold_wka_kernel<<<dim3(BATCH * NH * HID / 256), 256, 0, stream>>>(Wka, pq, WkaE);
  delta_kernel<<<dim3(BATCH * NH), 64, 0, stream>>>(WkaE, bk, bka, biask);
  v_kernel<<<dim3(BATCH, HID / 256), 256, 0, stream>>>(WkaE, Wk, vb);

  // 6. qk scores = Xb @ vb^T
  score_mfma_kernel<<<dim3(MTOT / 128), 256, 0, stream>>>(Xb, vb, biask, mask, qs, NH * HID, 1);

  // 7. softmax stats, pooled t over X, finalize pk
  softmax_stats_kernel<<<dim3(BATCH * NH), 256, 0, stream>>>(qs, stats);
  pool_k_partial_kernel<<<dim3(BATCH, 16), 256, 0, stream>>>(qs, stats, Xb, tacc);
  finalize_pk_kernel<<<dim3(BATCH, NH), 256, 0, stream>>>(tacc, Wk, bk, pq, pk);

  // 8. WtE = Wt ⊙ pk ; out = MQ @ WtE^T + bt + MQ
  fold_wt_kernel<<<dim3(BATCH * HID * HID / 1024), 256, 0, stream>>>(Wt, pk, WtE);
  gemm_final_kernel<<<dim3(MTOT / 128, HID / 128), 256, 0, stream>>>(MQ, WtE, bt, out);
}

// Round 5
// 710.459 us; speedup vs baseline: 2.6719x; 1.2999x over previous
//
#include <hip/hip_runtime.h>
#include <hip/hip_bf16.h>
#include <cstdint>
#include <cstddef>

typedef unsigned short u16;
typedef __attribute__((ext_vector_type(8))) short s16x8;
typedef __attribute__((ext_vector_type(8))) unsigned short u16x8;
typedef __attribute__((ext_vector_type(4))) unsigned short u16x4;
typedef __attribute__((ext_vector_type(4))) float f32x4;

#define DEVI static __device__ __forceinline__

constexpr int S = 4096, HID = 1024, NH = 16, HD = 64, BATCH = 8;
constexpr int MTOT = BATCH * S;  // 32768
constexpr float SCALE = 0.125f;  // 1/sqrt(64)

DEVI float bf2f(u16 u) {
  union { unsigned int i; float f; } v; v.i = ((unsigned int)u) << 16; return v.f;
}
DEVI u16 f2b(float f) {
  __hip_bfloat16 h = __float2bfloat16(f);
  return *reinterpret_cast<u16*>(&h);
}

// global -> LDS async copy, 16B per lane. LDS dest must be wave-uniform;
// HW scatters lane i at ldst + i*16.
DEVI void gld16(const u16* g, u16* ldst) {
  __builtin_amdgcn_global_load_lds(
      (const __attribute__((address_space(1))) unsigned int*)g,
      (__attribute__((address_space(3))) unsigned int*)ldst, 16, 0, 0);
}

// ---------------------------------------------------------------------------
// fp32 -> bf16 convert, 8 elems/thread
// ---------------------------------------------------------------------------
__global__ __launch_bounds__(256) void conv_bf16_kernel(
    const float* __restrict__ in, u16* __restrict__ out, int n)
{
  const size_t i = ((size_t)blockIdx.x * 256 + threadIdx.x) * 8;
  if (i >= (size_t)n) return;
  float4 a = *(const float4*)(in + i);
  float4 b = *(const float4*)(in + i + 4);
  u16x8 o;
  o[0] = f2b(a.x); o[1] = f2b(a.y); o[2] = f2b(a.z); o[3] = f2b(a.w);
  o[4] = f2b(b.x); o[5] = f2b(b.y); o[6] = f2b(b.z); o[7] = f2b(b.w);
  *(u16x8*)(out + i) = o;
}

// ---------------------------------------------------------------------------
// m97-structure bf16 GEMM: MQ = Xb @ Wqb^T + bq  (bf16 out)
// ---------------------------------------------------------------------------
__global__ __launch_bounds__(256) void gemm_mq_kernel(
    const u16* __restrict__ A, const u16* __restrict__ B,
    const float* __restrict__ bias, u16* __restrict__ C)
{
  __shared__ u16 lA[128 * 64];
  __shared__ u16 lB[128 * 64];
  const int m0 = blockIdx.x * 128, n0 = blockIdx.y * 128;
  const int t = threadIdx.x, lane = t & 63, wv = t >> 6;
  const int wm = wv >> 1, wn = wv & 1, lg = lane >> 4, lr = lane & 15;

  const f32x4 zero = {0.f, 0.f, 0.f, 0.f};
  f32x4 acc[4][4];
#pragma unroll
  for (int i = 0; i < 4; ++i)
#pragma unroll
    for (int j = 0; j < 4; ++j) acc[i][j] = zero;

  const u16* gA = A + (size_t)m0 * HID;
  const u16* gB = B + (size_t)n0 * HID;

  for (int k0 = 0; k0 < HID; k0 += 64) {
#pragma unroll
    for (int i = 0; i < 4; ++i) {
      const int c = i * 256 + t;          // chunk: row=c>>3, col=(c&7)*8
      gld16(gA + (size_t)(c >> 3) * HID + k0 + (c & 7) * 8, lA + i * 2048 + wv * 512);
      gld16(gB + (size_t)(c >> 3) * HID + k0 + (c & 7) * 8, lB + i * 2048 + wv * 512);
    }
    __syncthreads();
#pragma unroll
    for (int kk = 0; kk < 2; ++kk) {
      s16x8 af[4], bfv[4];
#pragma unroll
      for (int i = 0; i < 4; ++i)
        af[i] = *(const s16x8*)&lA[(wm * 64 + i * 16 + lr) * 64 + kk * 32 + lg * 8];
#pragma unroll
      for (int j = 0; j < 4; ++j)
        bfv[j] = *(const s16x8*)&lB[(wn * 64 + j * 16 + lr) * 64 + kk * 32 + lg * 8];
#pragma unroll
      for (int i = 0; i < 4; ++i)
#pragma unroll
        for (int j = 0; j < 4; ++j)
          acc[i][j] = __builtin_amdgcn_mfma_f32_16x16x32_bf16(af[i], bfv[j], acc[i][j], 0, 0, 0);
    }
    __syncthreads();
  }

#pragma unroll
  for (int i = 0; i < 4; ++i)
#pragma unroll
    for (int j = 0; j < 4; ++j) {
      const int n = n0 + wn * 64 + j * 16 + lr;
      const float bv = bias[n];
#pragma unroll
      for (int r = 0; r < 4; ++r) {
        const int m = m0 + wm * 64 + i * 16 + lg * 4 + r;
        C[(size_t)m * HID + n] = f2b(acc[i][j][r] + bv);
      }
    }
}

// ---------------------------------------------------------------------------
// Final GEMM: out = MQ @ WtE[b]^T + bt + fp32(MQ)   (fp32 out)
// ---------------------------------------------------------------------------
__global__ __launch_bounds__(256) void gemm_final_kernel(
    const u16* __restrict__ A, const u16* __restrict__ WtE,
    const float* __restrict__ bt, float* __restrict__ out)
{
  __shared__ u16 lA[128 * 64];
  __shared__ u16 lB[128 * 64];
  const int m0 = blockIdx.x * 128, n0 = blockIdx.y * 128;
  const int b = m0 >> 12;
  const u16* B = WtE + (size_t)b * HID * HID;
  const int t = threadIdx.x, lane = t & 63, wv = t >> 6;
  const int wm = wv >> 1, wn = wv & 1, lg = lane >> 4, lr = lane & 15;

  const f32x4 zero = {0.f, 0.f, 0.f, 0.f};
  f32x4 acc[4][4];
#pragma unroll
  for (int i = 0; i < 4; ++i)
#pragma unroll
    for (int j = 0; j < 4; ++j) acc[i][j] = zero;

  const u16* gA = A + (size_t)m0 * HID;
  const u16* gB = B + (size_t)n0 * HID;

  for (int k0 = 0; k0 < HID; k0 += 64) {
#pragma unroll
    for (int i = 0; i < 4; ++i) {
      const int c = i * 256 + t;
      gld16(gA + (size_t)(c >> 3) * HID + k0 + (c & 7) * 8, lA + i * 2048 + wv * 512);
      gld16(gB + (size_t)(c >> 3) * HID + k0 + (c & 7) * 8, lB + i * 2048 + wv * 512);
    }
    __syncthreads();
#pragma unroll
    for (int kk = 0; kk < 2; ++kk) {
      s16x8 af[4], bfv[4];
#pragma unroll
      for (int i = 0; i < 4; ++i)
        af[i] = *(const s16x8*)&lA[(wm * 64 + i * 16 + lr) * 64 + kk * 32 + lg * 8];
#pragma unroll
      for (int j = 0; j < 4; ++j)
        bfv[j] = *(const s16x8*)&lB[(wn * 64 + j * 16 + lr) * 64 + kk * 32 + lg * 8];
#pragma unroll
      for (int i = 0; i < 4; ++i)
#pragma unroll
        for (int j = 0; j < 4; ++j)
          acc[i][j] = __builtin_amdgcn_mfma_f32_16x16x32_bf16(af[i], bfv[j], acc[i][j], 0, 0, 0);
    }
    __syncthreads();
  }

#pragma unroll
  for (int i = 0; i < 4; ++i)
#pragma unroll
    for (int j = 0; j < 4; ++j) {
      const int n = n0 + wn * 64 + j * 16 + lr;
      const float bv = bt[n];
#pragma unroll
      for (int r = 0; r < 4; ++r) {
        const int m = m0 + wm * 64 + i * 16 + lg * 4 + r;
        out[(size_t)m * HID + n] = acc[i][j][r] + bv + bf2f(A[(size_t)m * HID + n]);
      }
    }
}

// ---------------------------------------------------------------------------
// Skinny score GEMM via MFMA: scores[b,h,s] = (A[m,:]·Bw[h,:] + bias)*SCALE + mask
// ---------------------------------------------------------------------------
__global__ __launch_bounds__(256) void score_mfma_kernel(
    const u16* __restrict__ A, const u16* __restrict__ Bw,
    const float* __restrict__ bias, const float* __restrict__ mask,
    float* __restrict__ scores, int bstride, int biasBH)
{
  __shared__ u16 lA[128 * 64];
  const int m0 = blockIdx.x * 128;
  const int b = m0 >> 12;
  const u16* B = Bw + (size_t)b * bstride;
  const int t = threadIdx.x, lane = t & 63, wv = t >> 6;
  const int lg = lane >> 4, lr = lane & 15;

  f32x4 acc0 = {0.f, 0.f, 0.f, 0.f}, acc1 = {0.f, 0.f, 0.f, 0.f};

  for (int k0 = 0; k0 < HID; k0 += 64) {
#pragma unroll
    for (int i = 0; i < 4; ++i) {
      const int c = i * 256 + t;
      gld16(A + (size_t)(m0 + (c >> 3)) * HID + k0 + (c & 7) * 8, lA + i * 2048 + wv * 512);
    }
    __syncthreads();
#pragma unroll
    for (int kk = 0; kk < 2; ++kk) {
      s16x8 bf = *(const s16x8*)(B + lr * HID + k0 + kk * 32 + lg * 8);
      s16x8 a0 = *(const s16x8*)&lA[(wv * 32 + lr) * 64 + kk * 32 + lg * 8];
      s16x8 a1 = *(const s16x8*)&lA[(wv * 32 + 16 + lr) * 64 + kk * 32 + lg * 8];
      acc0 = __builtin_amdgcn_mfma_f32_16x16x32_bf16(a0, bf, acc0, 0, 0, 0);
      acc1 = __builtin_amdgcn_mfma_f32_16x16x32_bf16(a1, bf, acc1, 0, 0, 0);
    }
    __syncthreads();
  }

  const int h = lr;
  const float bv = biasBH ? bias[b * 16 + h] : bias[h];
#pragma unroll
  for (int i = 0; i < 2; ++i) {
    f32x4 a = i ? acc1 : acc0;
#pragma unroll
    for (int r = 0; r < 4; ++r) {
      const int m = m0 + wv * 32 + i * 16 + lg * 4 + r;
      const int s = m & 4095;
      scores[((size_t)b * 16 + h) * S + s] = (a[r] + bv) * SCALE + mask[m];
    }
  }
}

// per (b,h): gmax and 1/sum(exp) over scores row
__global__ __launch_bounds__(256) void softmax_stats_kernel(
    const float* __restrict__ scores, float* __restrict__ stats)
{
  __shared__ float red[8];
  const int bh = blockIdx.x;
  const float* sc = scores + (size_t)bh * S;
  const int t = threadIdx.x, lane = t & 63, wv = t >> 6;
  float m = -3.4e38f;
  for (int i = t; i < S; i += 256) m = fmaxf(m, sc[i]);
#pragma unroll
  for (int o = 1; o < 64; o <<= 1) m = fmaxf(m, __shfl_xor(m, o));
  if (lane == 0) red[wv] = m;
  __syncthreads();
  const float gmax = fmaxf(fmaxf(red[0], red[1]), fmaxf(red[2], red[3]));
  float s = 0.f;
  for (int i = t; i < S; i += 256) s += __expf(sc[i] - gmax);
#pragma unroll
  for (int o = 1; o < 64; o <<= 1) s += __shfl_xor(s, o);
  if (lane == 0) red[4 + wv] = s;
  __syncthreads();
  if (t == 0) {
    stats[bh * 2] = gmax;
    stats[bh * 2 + 1] = 1.0f / (red[4] + red[5] + red[6] + red[7]);
  }
}

// ---------------------------------------------------------------------------
// pq[b,h*64+d] += sum_{s in chunk} exp(sc-g)*inv * MQ[b,s,h*64+d]
// grid (128 bh, 8 s-chunks of 512), atomic accumulate into zeroed pq.
// ---------------------------------------------------------------------------
__global__ __launch_bounds__(256) void pool_q_partial_kernel(
    const float* __restrict__ scores, const float* __restrict__ stats,
    const u16* __restrict__ MQ, float* __restrict__ pqacc)
{
  __shared__ float wl[512];
  __shared__ float rb[8][64];
  const int bh = blockIdx.x, b = bh >> 4, h = bh & 15;
  const int sc0 = blockIdx.y * 512;
  const int t = threadIdx.x;
  const float g = stats[bh * 2], inv = stats[bh * 2 + 1];
  const float* sc = scores + (size_t)bh * S + sc0;
  for (int i = t; i < 512; i += 256) wl[i] = __expf(sc[i] - g) * inv;
  __syncthreads();

  const int dp = (t & 31) * 2, sg = t >> 5;
  const u16* base = MQ + ((size_t)b * S + sc0) * HID + h * HD + dp;
  float a0 = 0.f, a1 = 0.f;
#pragma unroll 4
  for (int sl = sg; sl < 512; sl += 8) {
    const float ww = wl[sl];
    const unsigned int xv = *(const unsigned int*)(base + (size_t)sl * HID);
    a0 += ww * bf2f((u16)(xv & 0xffffu));
    a1 += ww * bf2f((u16)(xv >> 16));
  }
  rb[sg][dp] = a0; rb[sg][dp + 1] = a1;
  __syncthreads();
  if (t < 64) {
    float r = 0.f;
#pragma unroll
    for (int g2 = 0; g2 < 8; ++g2) r += rb[g2][t];
    atomicAdd(&pqacc[(size_t)b * HID + h * HD + t], r);
  }
}

// WkaE[b,h,c] = Wka[h,c] * pq[b,c]   (fp32)
__global__ __launch_bounds__(256) void fold_wka_kernel(
    const float* __restrict__ Wka, const float* __restrict__ pq,
    float* __restrict__ out)
{
  const int i = blockIdx.x * 256 + threadIdx.x;  // < 8*16*1024
  const int b = i >> 14, c = i & 1023, hc = i & 16383;
  out[i] = Wka[hc] * pq[b * HID + c];
}

// biask[b*16+h] = bka[h] + sum_c WkaE[b,h,c]*bk[c]
__global__ __launch_bounds__(64) void delta_kernel(
    const float* __restrict__ WkaE, const float* __restrict__ bk,
    const float* __restrict__ bka, float* __restrict__ biask)
{
  const int bh = blockIdx.x;
  const float* wr = WkaE + (size_t)bh * HID;
  float s = 0.f;
  for (int i = threadIdx.x; i < HID; i += 64) s += wr[i] * bk[i];
#pragma unroll
  for (int o = 1; o < 64; o <<= 1) s += __shfl_xor(s, o);
  if (threadIdx.x == 0) biask[bh] = bka[bh & 15] + s;
}

// ---------------------------------------------------------------------------
// vacc[b,h,c'] += sum_{c in chunk} WkaE[b,h,c] * Wk[c,c']  (k-split + atomics)
// grid (8, 4 cp-tiles, 8 k-chunks of 128)
// ---------------------------------------------------------------------------
__global__ __launch_bounds__(256) void v_split_kernel(
    const float* __restrict__ WkaE, const float* __restrict__ Wk,
    float* __restrict__ vacc)
{
  const int b = blockIdx.x;
  const int cp = blockIdx.y * 256 + threadIdx.x;
  const int c0 = blockIdx.z * 128;
  const float* wka = WkaE + (size_t)b * NH * HID;
  float acc[16];
#pragma unroll
  for (int h = 0; h < 16; ++h) acc[h] = 0.f;
  for (int c = c0; c < c0 + 128; ++c) {
    const float wkc = Wk[(size_t)c * HID + cp];
#pragma unroll
    for (int h = 0; h < 16; ++h) acc[h] += wka[h * HID + c] * wkc;
  }
#pragma unroll
  for (int h = 0; h < 16; ++h)
    atomicAdd(&vacc[((size_t)b * 16 + h) * HID + cp], acc[h]);
}

// ---------------------------------------------------------------------------
// tacc[b,h,c'] += sum_{s in chunk} w[b,h,s] * X[b,s,c']   (32 s-chunks of 128)
// ---------------------------------------------------------------------------
__global__ __launch_bounds__(256) void pool_k_partial_kernel(
    const float* __restrict__ scores, const float* __restrict__ stats,
    const u16* __restrict__ Xb, float* __restrict__ tacc)
{
  __shared__ float wl[16 * 128];
  const int b = blockIdx.x, sc0 = blockIdx.y * 128;
  const int t = threadIdx.x;
#pragma unroll
  for (int j = 0; j < 8; ++j) {
    const int idx = j * 256 + t;           // 0..2047
    const int h = idx >> 7, sl = idx & 127;
    const float g = stats[(b * 16 + h) * 2], inv = stats[(b * 16 + h) * 2 + 1];
    wl[idx] = __expf(scores[((size_t)b * 16 + h) * S + sc0 + sl] - g) * inv;
  }
  __syncthreads();

  float acc[16][4];
#pragma unroll
  for (int h = 0; h < 16; ++h)
#pragma unroll
    for (int j = 0; j < 4; ++j) acc[h][j] = 0.f;

  const u16* xp = Xb + ((size_t)(b * S + sc0)) * HID + t * 4;
  for (int sl = 0; sl < 128; ++sl) {
    u16x4 xv = *(const u16x4*)(xp + (size_t)sl * HID);
    const float x0 = bf2f(xv[0]), x1 = bf2f(xv[1]), x2 = bf2f(xv[2]), x3 = bf2f(xv[3]);
#pragma unroll
    for (int h = 0; h < 16; ++h) {
      const float ww = wl[h * 128 + sl];
      acc[h][0] += ww * x0; acc[h][1] += ww * x1;
      acc[h][2] += ww * x2; acc[h][3] += ww * x3;
    }
  }
#pragma unroll
  for (int h = 0; h < 16; ++h)
#pragma unroll
    for (int j = 0; j < 4; ++j)
      atomicAdd(&tacc[((size_t)b * 16 + h) * HID + t * 4 + j], acc[h][j]);
}

// pk[b,hd] = (t[b,h,:]·Wk[hd,:] + bk[hd]) * pq[b,hd]
__global__ __launch_bounds__(256) void finalize_pk_kernel(
    const float* __restrict__ tacc, const float* __restrict__ Wk,
    const float* __restrict__ bk, const float* __restrict__ pq,
    float* __restrict__ pk)
{
  __shared__ float ts[HID];
  const int b = blockIdx.x, h = blockIdx.y;
  const int t = threadIdx.x;
  const float* trow = tacc + ((size_t)b * 16 + h) * HID;
  for (int i = t; i < HID; i += 256) ts[i] = trow[i];
  __syncthreads();
  const int d = t >> 2, part = t & 3;
  const float* wrow = Wk + (size_t)(h * 64 + d) * HID + part * 256;
  float s = 0.f;
#pragma unroll 4
  for (int i = 0; i < 256; i += 4) {
    float4 w4 = *(const float4*)(wrow + i);
    s += ts[part * 256 + i] * w4.x + ts[part * 256 + i + 1] * w4.y +
         ts[part * 256 + i + 2] * w4.z + ts[part * 256 + i + 3] * w4.w;
  }
  s += __shfl_xor(s, 1);
  s += __shfl_xor(s, 2);
  if (part == 0) {
    const int hd = h * 64 + d;
    pk[b * HID + hd] = (s + bk[hd]) * pq[b * HID + hd];
  }
}

// WtE[b,n,c] = bf16(Wt[n,c] * pk[b,c])
__global__ __launch_bounds__(256) void fold_wt_kernel(
    const float* __restrict__ Wt, const float* __restrict__ pk,
    u16* __restrict__ WtE)
{
  const size_t j = ((size_t)blockIdx.x * 256 + threadIdx.x) * 4;  // < 8*1M
  const int b = (int)(j >> 20);
  const size_t r = j & 1048575;
  const int c = (int)(j & 1023);
  float4 w = *(const float4*)(Wt + r);
  float4 g = *(const float4*)(pk + b * HID + c);
  u16x4 o;
  o[0] = f2b(w.x * g.x); o[1] = f2b(w.y * g.y);
  o[2] = f2b(w.z * g.z); o[3] = f2b(w.w * g.w);
  *(u16x4*)(WtE + (size_t)b * HID * HID + r) = o;
}

// ---------------------------------------------------------------------------
extern "C" void kernel_launch(void* const* d_in, const int* in_sizes, int n_in,
                              void* d_out, int out_size, void* d_ws, size_t ws_size,
                              hipStream_t stream) {
  const float* X    = (const float*)d_in[0];
  const float* mask = (const float*)d_in[1];
  const float* Wq   = (const float*)d_in[2];
  const float* bq   = (const float*)d_in[3];
  const float* Wqa  = (const float*)d_in[4];
  const float* bqa  = (const float*)d_in[5];
  const float* Wk   = (const float*)d_in[6];
  const float* bk   = (const float*)d_in[7];
  const float* Wka  = (const float*)d_in[8];
  const float* bka  = (const float*)d_in[9];
  const float* Wt   = (const float*)d_in[10];
  const float* bt   = (const float*)d_in[11];
  float* out = (float*)d_out;

  // Xb (bf16 X) lives in d_out: dead before gemm_final writes out.
  u16* Xb = (u16*)d_out;

  char* ws = (char*)d_ws;
  u16* MQ     = (u16*)ws;   ws += (size_t)MTOT * HID * 2;       // 67.1MB
  u16* Wqb    = (u16*)ws;   ws += (size_t)HID * HID * 2;        // 2MB
  u16* Wqab   = (u16*)ws;   ws += (size_t)NH * HID * 2;         // 32KB
  u16* vb     = (u16*)ws;   ws += (size_t)BATCH * NH * HID * 2; // 256KB
  u16* WtE    = (u16*)ws;   ws += (size_t)BATCH * HID * HID * 2;// 16.8MB
  float* qs   = (float*)ws; ws += (size_t)BATCH * NH * S * 4;   // 2MB
  float* WkaE = (float*)ws; ws += (size_t)BATCH * NH * HID * 4; // 512KB
  float* stats= (float*)ws; ws += (size_t)BATCH * NH * 2 * 4;
  float* biask= (float*)ws; ws += (size_t)BATCH * NH * 4;
  float* pk   = (float*)ws; ws += (size_t)BATCH * HID * 4;
  // --- zeroed region (atomic accumulators), contiguous ---
  char* zbase = ws;
  float* pq   = (float*)ws; ws += (size_t)BATCH * HID * 4;       // 32KB
  float* tacc = (float*)ws; ws += (size_t)BATCH * NH * HID * 4;  // 512KB
  float* vacc = (float*)ws; ws += (size_t)BATCH * NH * HID * 4;  // 512KB
  const size_t zbytes = (size_t)(ws - zbase);

  hipMemsetAsync(zbase, 0, zbytes, stream);

  // 1. convert to bf16
  conv_bf16_kernel<<<dim3(MTOT * HID / 2048), 256, 0, stream>>>(X, Xb, MTOT * HID);
  conv_bf16_kernel<<<dim3(HID * HID / 2048), 256, 0, stream>>>(Wq, Wqb, HID * HID);
  conv_bf16_kernel<<<dim3(NH * HID / 2048), 256, 0, stream>>>(Wqa, Wqab, NH * HID);

  // 2. MQ = Xb@Wqb^T + bq
  gemm_mq_kernel<<<dim3(MTOT / 128, HID / 128), 256, 0, stream>>>(Xb, Wqb, bq, MQ);

  // 3. q scores
  score_mfma_kernel<<<dim3(MTOT / 128), 256, 0, stream>>>(MQ, Wqab, bqa, mask, qs, 0, 0);

  // 4. softmax stats + chunked pool -> pq (normalized via inv folded into w)
  softmax_stats_kernel<<<dim3(BATCH * NH), 256, 0, stream>>>(qs, stats);
  pool_q_partial_kernel<<<dim3(BATCH * NH, S / 512), 256, 0, stream>>>(qs, stats, MQ, pq);

  // 5. WkaE = Wka ⊙ pq ; folded k-bias ; vacc = WkaE @ Wk (k-split) ; vb = bf16(vacc)
  fold_wka_kernel<<<dim3(BATCH * NH * HID / 256), 256, 0, stream>>>(Wka, pq, WkaE);
  delta_kernel<<<dim3(BATCH * NH), 64, 0, stream>>>(WkaE, bk, bka, biask);
  v_split_kernel<<<dim3(BATCH, HID / 256, 8), 256, 0, stream>>>(WkaE, Wk, vacc);
  conv_bf16_kernel<<<dim3(BATCH * NH * HID / 2048), 256, 0, stream>>>(vacc, vb, BATCH * NH * HID);

  // 6. qk scores = Xb @ vb^T
  score_mfma_kernel<<<dim3(MTOT / 128), 256, 0, stream>>>(Xb, vb, biask, mask, qs, NH * HID, 1);

  // 7. softmax stats, pooled t over X (32 chunks), finalize pk
  softmax_stats_kernel<<<dim3(BATCH * NH), 256, 0, stream>>>(qs, stats);
  pool_k_partial_kernel<<<dim3(BATCH, S / 128), 256, 0, stream>>>(qs, stats, Xb, tacc);
  finalize_pk_kernel<<<dim3(BATCH, NH), 256, 0, stream>>>(tacc, Wk, bk, pq, pk);

  // 8. WtE = Wt ⊙ pk ; out = MQ @ WtE^T + bt + MQ
  fold_wt_kernel<<<dim3(BATCH * HID * HID / 1024), 256, 0, stream>>>(Wt, pk, WtE);
  gemm_final_kernel<<<dim3(MTOT / 128, HID / 128), 256, 0, stream>>>(MQ, WtE, bt, out);
}